// Round 10
// baseline (212.398 us; speedup 1.0000x reference)
//
#include <hip/hip_runtime.h>
#include <math.h>

#define EMBED   256
#define M_HEADS 8
#define DVAL    32
#define LK      16
#define S_TOTAL 21760
#define NQ      8192
#define NROWS   (2 * NQ)          // 16384 total query rows
#define QBS     32                // queries per block (sample)

typedef __attribute__((ext_vector_type(8))) short s16x8;
typedef __attribute__((ext_vector_type(4))) float f32x4;
typedef unsigned short u16;
typedef unsigned int   u32;

__device__ __forceinline__ short f2bf(float f) {
    unsigned u = __float_as_uint(f);
    u += 0x7fffu + ((u >> 16) & 1u);
    return (short)(u >> 16);
}
__device__ __forceinline__ float bf2f(short h) {
    return __uint_as_float(((unsigned)(u16)h) << 16);
}

// ---------------- workspace layout (float offsets) ----------------
#define V_OFF     0                      // value table, bf16: 11,141,120 shorts
#define V_FLTS    5570560
#define PA_OFF    (V_OFF + V_FLTS)       // (x,y,attn) fp32 triples
#define PA_FLTS   6291456
#define MID_OFF   (PA_OFF + PA_FLTS)     // mid bf16 [16384][256]
#define MID_FLTS  2097152
#define WHI_OFF   (MID_OFF + MID_FLTS)   // packed [W_off|W_attn] hi, C=384
#define WOA_FLTS  49152
#define WLO_OFF   (WHI_OFF + WOA_FLTS)
#define WV_OFF    (WLO_OFF + WOA_FLTS)   // packed W_val bf16, C=256
#define WO_OFF    (WV_OFF + 32768)       // packed W_out bf16, C=256

// ---------------------------------------------------------------------------
// prep_kernel (weight packs only): blocks 0..511 pack W_val/W_out (C=256),
// blocks 512..895 pack [W_off|W_attn] hi/lo (C=384).
// ---------------------------------------------------------------------------
__global__ __launch_bounds__(256) void prep_kernel(
    const float* __restrict__ W_off, const float* __restrict__ W_attn,
    u16* __restrict__ Whi,           u16* __restrict__ Wlo,
    const float* __restrict__ W_val, u16* __restrict__ Wv,
    const float* __restrict__ W_out, u16* __restrict__ Wo)
{
    const int b = blockIdx.x;
    const int t = threadIdx.x;

    if (b < 512) {                        // pack W_val / W_out (C=256)
        const int flat = b * 256 + t;                // 0..131071
        const int which = flat >> 16;                // 0: W_val, 1: W_out
        const int e = flat & 65535;
        const int k = e >> 8, c = e & 255;
        const float f = which ? W_out[k * 256 + c] : W_val[k * 256 + c];
        const int kt = k >> 5, qd = (k >> 3) & 3, j = k & 7;
        const int idx = (((kt * 256 + c) << 2) + qd) * 8 + j;
        (which ? Wo : Wv)[idx] = (u16)f2bf(f);
    } else {                              // pack [W_off|W_attn] hi/lo (C=384)
        const int flat = (b - 512) * 256 + t;        // 0..98303
        const int k = flat / 384, c = flat - k * 384;
        const float f = (c < 256) ? W_off[k * 256 + c] : W_attn[k * 128 + (c - 256)];
        const short h = f2bf(f);
        const short lo = f2bf(f - bf2f(h));
        const int kt = k >> 5, qd = (k >> 3) & 3, j = k & 7;
        const int idx = (((kt * 384 + c) << 2) + qd) * 8 + j;
        Whi[idx] = (u16)h;
        Wlo[idx] = (u16)lo;
    }
}

// ---------------------------------------------------------------------------
// stage1_kernel: vproj (blocks 0..511) + qproj (blocks 512..1023) fused in
// one launch so memory-latency-leaning vproj waves co-schedule with
// MFMA-bound qproj waves on the same CUs (independent work, m114 overlap).
//
// vproj path: per-head bf16 v_out = mask * (value @ W_val + b_val).
//   Wave owns 64 cols; all 32 B-frags preloaded once; grid-stride over
//   2720 16-row A-tiles.
// qproj path: [offsets|attn] = q @ [W_off|W_attn] + bias via 3-pass hi/lo
//   split-bf16 MFMA (fp32-grade), then softmax + position math -> pa.
// ---------------------------------------------------------------------------
__global__ __launch_bounds__(256, 2) void stage1_kernel(
    const float* __restrict__ value,
    const float* __restrict__ vmask,
    const u16* __restrict__ Wpk,
    const float* __restrict__ b_val,
    u16* __restrict__ v_out,
    const float* __restrict__ queries,
    const float* __restrict__ qgl,
    const u16* __restrict__ Whi, const u16* __restrict__ Wlo,
    const float* __restrict__ b_off, const float* __restrict__ b_attn,
    float* __restrict__ pa)
{
    __shared__ float s_off[32][260];
    __shared__ float s_attn[32][132];
    __shared__ float s_geom[32][4];

    const int t  = threadIdx.x;
    const int w  = t >> 6, l = t & 63;
    const int c  = l & 15, qd = l >> 4;

    if (blockIdx.x < 512) {
        // ---------------- vproj path ----------------
        const int c0 = w * 64;

        s16x8 B[8][4];
        #pragma unroll
        for (int kt = 0; kt < 8; ++kt)
            #pragma unroll
            for (int nt = 0; nt < 4; ++nt)
                B[kt][nt] = *(const s16x8*)(Wpk + (((kt * 256 + c0 + nt * 16 + c) << 2) + qd) * 8);

        float bias[4];
        #pragma unroll
        for (int nt = 0; nt < 4; ++nt) bias[nt] = b_val[c0 + nt * 16 + c];

        for (int tile = blockIdx.x; tile < 2720; tile += 512) {
            const int r0 = tile * 16;
            const float* __restrict__ ap = value + (size_t)(r0 + c) * EMBED + qd * 8;

            float4 a0[8], a1[8];
            #pragma unroll
            for (int kt = 0; kt < 8; ++kt) {
                a0[kt] = *(const float4*)(ap + kt * 32);
                a1[kt] = *(const float4*)(ap + kt * 32 + 4);
            }

            f32x4 acc[4] = {};
            #pragma unroll
            for (int kt = 0; kt < 8; ++kt) {
                const s16x8 a = (s16x8){ f2bf(a0[kt].x), f2bf(a0[kt].y), f2bf(a0[kt].z), f2bf(a0[kt].w),
                                         f2bf(a1[kt].x), f2bf(a1[kt].y), f2bf(a1[kt].z), f2bf(a1[kt].w) };
                #pragma unroll
                for (int nt = 0; nt < 4; ++nt)
                    acc[nt] = __builtin_amdgcn_mfma_f32_16x16x32_bf16(a, B[kt][nt], acc[nt], 0, 0, 0);
            }

            #pragma unroll
            for (int r = 0; r < 4; ++r) {
                const int grow = r0 + qd * 4 + r;
                const int n = (grow >= S_TOTAL) ? 1 : 0;
                const int s = grow - n * S_TOTAL;
                const float mk = vmask[grow];
                #pragma unroll
                for (int nt = 0; nt < 4; ++nt) {
                    const int col = c0 + nt * 16 + c;
                    const int hm = col >> 5, d = col & 31;
                    v_out[((size_t)(n * M_HEADS + hm) * S_TOTAL + s) * DVAL + d] =
                        (u16)f2bf((acc[nt][r] + bias[nt]) * mk);
                }
            }
        }
        return;
    }

    // ---------------- qproj path ----------------
    const int row0 = (blockIdx.x - 512) * 32;
    const int c0 = w * 96;

    if (t < 32) {
        const float* g = &qgl[(size_t)(row0 + t) * 4];
        s_geom[t][0] = 1.f / (1.f + __expf(-g[0]));
        s_geom[t][1] = 1.f / (1.f + __expf(-g[1]));
        s_geom[t][2] = (1.f / (1.f + __expf(-g[2]))) * 0.125f;
        s_geom[t][3] = (1.f / (1.f + __expf(-g[3]))) * 0.125f;
    }

    f32x4 acc[2][6] = {};

    for (int kt = 0; kt < 8; ++kt) {
        s16x8 ah[2], al[2], bh[6], bl[6];
        #pragma unroll
        for (int mt = 0; mt < 2; ++mt) {
            const float* qp = queries + (size_t)(row0 + mt * 16 + c) * EMBED + kt * 32 + qd * 8;
            const float4 v0 = *(const float4*)qp;
            const float4 v1 = *(const float4*)(qp + 4);
            const short h0 = f2bf(v0.x), h1 = f2bf(v0.y), h2 = f2bf(v0.z), h3 = f2bf(v0.w);
            const short h4 = f2bf(v1.x), h5 = f2bf(v1.y), h6 = f2bf(v1.z), h7 = f2bf(v1.w);
            ah[mt] = (s16x8){ h0, h1, h2, h3, h4, h5, h6, h7 };
            al[mt] = (s16x8){ f2bf(v0.x - bf2f(h0)), f2bf(v0.y - bf2f(h1)),
                              f2bf(v0.z - bf2f(h2)), f2bf(v0.w - bf2f(h3)),
                              f2bf(v1.x - bf2f(h4)), f2bf(v1.y - bf2f(h5)),
                              f2bf(v1.z - bf2f(h6)), f2bf(v1.w - bf2f(h7)) };
        }
        #pragma unroll
        for (int nt = 0; nt < 6; ++nt) {
            const int idx = (((kt * 384 + c0 + nt * 16 + c) << 2) + qd) * 8;
            bh[nt] = *(const s16x8*)(Whi + idx);
            bl[nt] = *(const s16x8*)(Wlo + idx);
        }
        #pragma unroll
        for (int mt = 0; mt < 2; ++mt)
            #pragma unroll
            for (int nt = 0; nt < 6; ++nt) {
                acc[mt][nt] = __builtin_amdgcn_mfma_f32_16x16x32_bf16(ah[mt], bh[nt], acc[mt][nt], 0, 0, 0);
                acc[mt][nt] = __builtin_amdgcn_mfma_f32_16x16x32_bf16(ah[mt], bl[nt], acc[mt][nt], 0, 0, 0);
                acc[mt][nt] = __builtin_amdgcn_mfma_f32_16x16x32_bf16(al[mt], bh[nt], acc[mt][nt], 0, 0, 0);
            }
    }

    #pragma unroll
    for (int mt = 0; mt < 2; ++mt)
        #pragma unroll
        for (int nt = 0; nt < 6; ++nt) {
            const int col = c0 + nt * 16 + c;
            #pragma unroll
            for (int r = 0; r < 4; ++r) {
                const int row = mt * 16 + qd * 4 + r;
                if (col < 256) s_off[row][col] = acc[mt][nt][r] + b_off[col];
                else           s_attn[row][col - 256] = acc[mt][nt][r] + b_attn[col - 256];
            }
        }
    __syncthreads();

    {
        const int qi = t >> 3, hm = t & 7;
        float* a = &s_attn[qi][hm * LK];
        float mx = a[0];
        #pragma unroll
        for (int i = 1; i < LK; ++i) mx = fmaxf(mx, a[i]);
        float s = 0.f;
        #pragma unroll
        for (int i = 0; i < LK; ++i) { const float e = __expf(a[i] - mx); a[i] = e; s += e; }
        const float inv = 1.f / s;
        #pragma unroll
        for (int i = 0; i < LK; ++i) a[i] *= inv;
    }
    __syncthreads();

    for (int p = t; p < 32 * 128; p += 256) {
        const int qi = p >> 7;
        const int pt = p & 127;
        const int lvl = (pt & 15) >> 2;
        const float Wl = (float)(128 >> lvl);
        const float px = fmaf(s_off[qi][2 * pt + 0], s_geom[qi][2], s_geom[qi][0]);
        const float py = fmaf(s_off[qi][2 * pt + 1], s_geom[qi][3], s_geom[qi][1]);
        const float gx = fminf(fmaxf(2.f * px - 1.f, -1.f), 1.f);
        const float gy = fminf(fmaxf(2.f * py - 1.f, -1.f), 1.f);
        const float x = (gx + 1.f) * (Wl * 0.5f) - 0.5f;
        const float y = (gy + 1.f) * (Wl * 0.5f) - 0.5f;
        const size_t idx = ((size_t)(row0 + qi) * 128 + pt) * 3;
        pa[idx + 0] = x;
        pa[idx + 1] = y;
        pa[idx + 2] = s_attn[qi][pt];
    }
}

// ---------------------------------------------------------------------------
// Kernel 3: bilinear sampling, 4 channels per lane via 8-byte gathers.
// Block = 32 queries x one head. Setup: 512 points (2/thread) -> LDS int4
// offsets + float4 attn-folded weights. Main: g = t>>3 query, dp = t&7
// channel quad; uint2 gathers pull 4 bf16 channels per corner.
// m = blk&7 keeps one head's slice L2-local per XCD.
// ---------------------------------------------------------------------------
__global__ __launch_bounds__(256) void sample_kernel(
    const float* __restrict__ pa,
    const u16* __restrict__ v_tab,
    u16* __restrict__ mid)
{
    __shared__ int4   s_idx[QBS * LK];   // 8 KiB
    __shared__ float4 s_w[QBS * LK];     // 8 KiB

    const int t    = threadIdx.x;
    const int m    = blockIdx.x & 7;
    const int rest = blockIdx.x >> 3;
    const int qc   = rest & 255;
    const int n    = rest >> 8;
    const int q0   = qc * QBS;

    // ---- setup: 2 points per thread ----
    #pragma unroll
    for (int pp = 0; pp < 2; ++pp) {
        const int e  = t + pp * 256;
        const int qi = e >> 4, lk = e & 15;
        const int lvl   = lk >> 2;
        const int Wl    = 128 >> lvl;
        const int start = (lvl == 0) ? 0 : (lvl == 1) ? 16384 : (lvl == 2) ? 20480 : 21504;

        const size_t prow = ((size_t)(n * NQ + q0 + qi)) * 128 + m * 16 + lk;
        const float x  = pa[prow * 3 + 0];
        const float y  = pa[prow * 3 + 1];
        const float aw = pa[prow * 3 + 2];

        const float x0f = floorf(x), y0f = floorf(y);
        const int   x0 = (int)x0f, y0 = (int)y0f;
        const float wx = x - x0f, wy = y - y0f;

        const float vx0 = (x0 >= 0) ? 1.f : 0.f;
        const float vx1 = (x0 + 1 <= Wl - 1) ? 1.f : 0.f;
        const float vy0 = (y0 >= 0) ? 1.f : 0.f;
        const float vy1 = (y0 + 1 <= Wl - 1) ? 1.f : 0.f;

        const int xc0 = max(x0, 0);
        const int xc1 = min(x0 + 1, Wl - 1);
        const int yc0 = max(y0, 0);
        const int yc1 = min(y0 + 1, Wl - 1);

        s_idx[e] = make_int4((start + yc0 * Wl + xc0) * DVAL,
                             (start + yc0 * Wl + xc1) * DVAL,
                             (start + yc1 * Wl + xc0) * DVAL,
                             (start + yc1 * Wl + xc1) * DVAL);
        s_w[e] = make_float4(aw * (1.f - wx) * (1.f - wy) * vx0 * vy0,
                             aw * wx * (1.f - wy) * vx1 * vy0,
                             aw * (1.f - wx) * wy * vx0 * vy1,
                             aw * wx * wy * vx1 * vy1);
    }
    __syncthreads();

    const int g = t >> 3, dp = t & 7;
    const u16* __restrict__ vbp =
        v_tab + (size_t)(n * M_HEADS + m) * S_TOTAL * DVAL + 4 * dp;

    float acc0 = 0.f, acc1 = 0.f, acc2 = 0.f, acc3 = 0.f;
    #pragma unroll
    for (int lk = 0; lk < LK; ++lk) {
        const int4   id = s_idx[g * LK + lk];
        const float4 w  = s_w[g * LK + lk];
        const uint2 u0 = *(const uint2*)(vbp + id.x);
        const uint2 u1 = *(const uint2*)(vbp + id.y);
        const uint2 u2 = *(const uint2*)(vbp + id.z);
        const uint2 u3 = *(const uint2*)(vbp + id.w);
        acc0 = fmaf(w.x, __uint_as_float(u0.x << 16), acc0);
        acc1 = fmaf(w.x, __uint_as_float(u0.x & 0xffff0000u), acc1);
        acc2 = fmaf(w.x, __uint_as_float(u0.y << 16), acc2);
        acc3 = fmaf(w.x, __uint_as_float(u0.y & 0xffff0000u), acc3);
        acc0 = fmaf(w.y, __uint_as_float(u1.x << 16), acc0);
        acc1 = fmaf(w.y, __uint_as_float(u1.x & 0xffff0000u), acc1);
        acc2 = fmaf(w.y, __uint_as_float(u1.y << 16), acc2);
        acc3 = fmaf(w.y, __uint_as_float(u1.y & 0xffff0000u), acc3);
        acc0 = fmaf(w.z, __uint_as_float(u2.x << 16), acc0);
        acc1 = fmaf(w.z, __uint_as_float(u2.x & 0xffff0000u), acc1);
        acc2 = fmaf(w.z, __uint_as_float(u2.y << 16), acc2);
        acc3 = fmaf(w.z, __uint_as_float(u2.y & 0xffff0000u), acc3);
        acc0 = fmaf(w.w, __uint_as_float(u3.x << 16), acc0);
        acc1 = fmaf(w.w, __uint_as_float(u3.x & 0xffff0000u), acc1);
        acc2 = fmaf(w.w, __uint_as_float(u3.y << 16), acc2);
        acc3 = fmaf(w.w, __uint_as_float(u3.y & 0xffff0000u), acc3);
    }

    uint2 packed;
    packed.x = ((u32)(u16)f2bf(acc1) << 16) | (u32)(u16)f2bf(acc0);
    packed.y = ((u32)(u16)f2bf(acc3) << 16) | (u32)(u16)f2bf(acc2);
    *(uint2*)(mid + ((size_t)(n * NQ + q0 + g)) * EMBED + m * DVAL + 4 * dp) = packed;
}

// ---------------------------------------------------------------------------
// Kernel 4 (MFMA, B-resident): out = mid @ W_out + b_out. Wave owns 64 cols,
// 32 B-frags preloaded once, grid-stride over 16-row A-tiles.
// ---------------------------------------------------------------------------
__global__ __launch_bounds__(256, 2) void out_kernel(
    const u16* __restrict__ mid,
    const u16* __restrict__ Wpk,
    const float* __restrict__ b_out,
    float* __restrict__ out)
{
    const int t  = threadIdx.x;
    const int w  = t >> 6, l = t & 63;
    const int c  = l & 15, qd = l >> 4;
    const int c0 = w * 64;

    s16x8 B[8][4];
    #pragma unroll
    for (int kt = 0; kt < 8; ++kt)
        #pragma unroll
        for (int nt = 0; nt < 4; ++nt)
            B[kt][nt] = *(const s16x8*)(Wpk + (((kt * 256 + c0 + nt * 16 + c) << 2) + qd) * 8);

    float bias[4];
    #pragma unroll
    for (int nt = 0; nt < 4; ++nt) bias[nt] = b_out[c0 + nt * 16 + c];

    for (int tile = blockIdx.x; tile < 1024; tile += 512) {
        const int r0 = tile * 16;
        const u16* __restrict__ ap = mid + (size_t)(r0 + c) * EMBED + qd * 8;

        s16x8 a[8];
        #pragma unroll
        for (int kt = 0; kt < 8; ++kt)
            a[kt] = *(const s16x8*)(ap + kt * 32);

        f32x4 acc[4] = {};
        #pragma unroll
        for (int kt = 0; kt < 8; ++kt)
            #pragma unroll
            for (int nt = 0; nt < 4; ++nt)
                acc[nt] = __builtin_amdgcn_mfma_f32_16x16x32_bf16(a[kt], B[kt][nt], acc[nt], 0, 0, 0);

        #pragma unroll
        for (int r = 0; r < 4; ++r) {
            const int row = r0 + qd * 4 + r;
            #pragma unroll
            for (int nt = 0; nt < 4; ++nt)
                out[(size_t)row * EMBED + c0 + nt * 16 + c] = acc[nt][r] + bias[nt];
        }
    }
}

// ---------------------------------------------------------------------------
extern "C" void kernel_launch(void* const* d_in, const int* in_sizes, int n_in,
                              void* d_out, int out_size, void* d_ws, size_t ws_size,
                              hipStream_t stream) {
    (void)in_sizes; (void)n_in; (void)out_size; (void)ws_size;

    const float* queries = (const float*)d_in[0];
    const float* qgl     = (const float*)d_in[1];
    const float* value   = (const float*)d_in[2];
    const float* vmask   = (const float*)d_in[3];
    const float* W_off   = (const float*)d_in[4];
    const float* b_off   = (const float*)d_in[5];
    const float* W_attn  = (const float*)d_in[6];
    const float* b_attn  = (const float*)d_in[7];
    const float* W_val   = (const float*)d_in[8];
    const float* b_val   = (const float*)d_in[9];
    const float* W_out   = (const float*)d_in[10];
    const float* b_out   = (const float*)d_in[11];

    float* ws   = (float*)d_ws;
    u16*  v_ws  = (u16*)(ws + V_OFF);
    float* pa   = ws + PA_OFF;
    u16*  mid   = (u16*)(ws + MID_OFF);
    u16*  whi   = (u16*)(ws + WHI_OFF);
    u16*  wlo   = (u16*)(ws + WLO_OFF);
    u16*  wvpk  = (u16*)(ws + WV_OFF);
    u16*  wopk  = (u16*)(ws + WO_OFF);
    float* outp = (float*)d_out;

    prep_kernel<<<896, 256, 0, stream>>>(W_off, W_attn, whi, wlo,
                                         W_val, wvpk, W_out, wopk);

    stage1_kernel<<<1024, 256, 0, stream>>>(value, vmask, wvpk, b_val, v_ws,
                                            queries, qgl, whi, wlo,
                                            b_off, b_attn, pa);
    sample_kernel<<<2 * (NQ / QBS) * M_HEADS, 256, 0, stream>>>(pa, v_ws, mid);
    out_kernel<<<512, 256, 0, stream>>>(mid, wopk, b_out, outp);
}